// Round 1
// baseline (636.440 us; speedup 1.0000x reference)
//
#include <hip/hip_runtime.h>
#include <hip/hip_bf16.h>
#include <math.h>

#define D_ 1024
#define THREE_D 3072
#define B_ 32
#define T_ 2048

// ---------------------------------------------------------------------------
// K1: LayerNorm over concat([raw_g, spec_g, rel_g]) per batch.
// Writes normalized result TRANSPOSED: gnT[k*32 + b], so K2 can read the 32
// batch values for a given k as 8 contiguous float4s.
// ---------------------------------------------------------------------------
__global__ __launch_bounds__(256) void ln_kernel(
    const float* __restrict__ raw_g, const float* __restrict__ spec_g,
    const float* __restrict__ rel_g, const float* __restrict__ gamma,
    const float* __restrict__ beta, float* __restrict__ gnT) {
  const int b = blockIdx.x;
  const int tid = threadIdx.x;
  __shared__ float sg[THREE_D];
  __shared__ float red[8];
  __shared__ float stats[2];

  float s = 0.f, s2 = 0.f;
#pragma unroll
  for (int i = 0; i < 12; ++i) {
    int k = i * 256 + tid;
    float v;
    if (k < 1024)       v = raw_g[b * 1024 + k];
    else if (k < 2048)  v = spec_g[b * 1024 + (k - 1024)];
    else                v = rel_g[b * 1024 + (k - 2048)];
    sg[k] = v;
    s += v;
    s2 += v * v;
  }
#pragma unroll
  for (int off = 32; off; off >>= 1) {
    s  += __shfl_down(s, off, 64);
    s2 += __shfl_down(s2, off, 64);
  }
  const int wv = tid >> 6;
  if ((tid & 63) == 0) { red[wv] = s; red[4 + wv] = s2; }
  __syncthreads();
  if (tid == 0) {
    float ts  = red[0] + red[1] + red[2] + red[3];
    float ts2 = red[4] + red[5] + red[6] + red[7];
    float mu  = ts * (1.0f / THREE_D);
    float var = ts2 * (1.0f / THREE_D) - mu * mu;
    stats[0] = mu;
    stats[1] = rsqrtf(var + 1e-5f);
  }
  __syncthreads();
  const float mu = stats[0], rstd = stats[1];
#pragma unroll
  for (int i = 0; i < 12; ++i) {
    int k = i * 256 + tid;
    gnT[k * 32 + b] = (sg[k] - mu) * rstd * gamma[k] + beta[k];
  }
}

// ---------------------------------------------------------------------------
// K2: partial GEMM  h_pre[b][j] = sum_k gnT[k][b] * w1[k][j]
// Grid (16 jt, 16 ks), 256 threads = 4 waves. Each wave: 64 j (lane), one
// 48-wide k slice (slice = ks*4 + waveId, 64 slices), all 32 b in registers.
// w1 is read exactly once total (12.6 MB). Partials: [64][32][1024] f32.
// ---------------------------------------------------------------------------
__global__ __launch_bounds__(256) void gate_gemm(
    const float* __restrict__ gnT, const float* __restrict__ w1,
    float* __restrict__ partials) {
  const int lane = threadIdx.x & 63;
  const int wvid = threadIdx.x >> 6;
  const int j = blockIdx.x * 64 + lane;
  const int slice = blockIdx.y * 4 + wvid;     // 0..63
  const int k0 = slice * 48;

  float4 acc[8];
#pragma unroll
  for (int i = 0; i < 8; ++i) acc[i] = make_float4(0.f, 0.f, 0.f, 0.f);

  for (int kk = 0; kk < 48; ++kk) {
    const int k = k0 + kk;
    const float wv = w1[k * D_ + j];                       // coalesced (lane=j)
    const float4* gp = (const float4*)(gnT + k * 32);      // wave-uniform, L1 broadcast
#pragma unroll
    for (int i = 0; i < 8; ++i) {
      float4 g = gp[i];
      acc[i].x = fmaf(g.x, wv, acc[i].x);
      acc[i].y = fmaf(g.y, wv, acc[i].y);
      acc[i].z = fmaf(g.z, wv, acc[i].z);
      acc[i].w = fmaf(g.w, wv, acc[i].w);
    }
  }
  float* base = partials + (size_t)slice * (B_ * D_) + j;
#pragma unroll
  for (int i = 0; i < 8; ++i) {
    base[(4 * i + 0) * D_] = acc[i].x;   // coalesced per b
    base[(4 * i + 1) * D_] = acc[i].y;
    base[(4 * i + 2) * D_] = acc[i].z;
    base[(4 * i + 3) * D_] = acc[i].w;
  }
}

// ---------------------------------------------------------------------------
// K3: reduce 64 k-slices, +b1, exact GELU, dot with w2, sigmoid -> alpha[b].
// One block per batch.
// ---------------------------------------------------------------------------
__global__ __launch_bounds__(256) void gate_finish(
    const float* __restrict__ partials, const float* __restrict__ b1,
    const float* __restrict__ w2, const float* __restrict__ b2,
    float* __restrict__ alpha_out) {
  const int b = blockIdx.x;
  const int tid = threadIdx.x;
  float contrib = 0.f;
#pragma unroll
  for (int i = 0; i < 4; ++i) {
    const int j = i * 256 + tid;
    float s = b1[j];
    for (int sl = 0; sl < 64; ++sl)
      s += partials[((size_t)sl * B_ + b) * D_ + j];       // coalesced
    // exact GELU: 0.5*x*(1+erf(x/sqrt(2)))
    float h = 0.5f * s * (1.0f + erff(s * 0.7071067811865476f));
    contrib += h * w2[j];
  }
  __shared__ float red[4];
#pragma unroll
  for (int off = 32; off; off >>= 1) contrib += __shfl_down(contrib, off, 64);
  if ((tid & 63) == 0) red[tid >> 6] = contrib;
  __syncthreads();
  if (tid == 0) {
    float tot = red[0] + red[1] + red[2] + red[3] + b2[0];
    alpha_out[b] = 1.0f / (1.0f + expf(-tot));
  }
}

// ---------------------------------------------------------------------------
// K4: main_repr = raw_residual + alpha[b] * rel_residual  (memory-bound).
// Grid (1024, B). Each thread: 2 float4, stride 262144 f4 within batch.
// ---------------------------------------------------------------------------
__global__ __launch_bounds__(256) void fuse_kernel(
    const float4* __restrict__ raw, const float4* __restrict__ rel,
    const float* __restrict__ alpha, float4* __restrict__ out) {
  const int b = blockIdx.y;
  const float a = alpha[b];                     // block-uniform
  const size_t f4_per_b = (size_t)T_ * D_ / 4;  // 524288
  size_t i0 = (size_t)b * f4_per_b + (size_t)blockIdx.x * 256 + threadIdx.x;
  size_t i1 = i0 + f4_per_b / 2;                // +262144
  float4 r0 = raw[i0], e0 = rel[i0];
  float4 r1 = raw[i1], e1 = rel[i1];
  float4 o0, o1;
  o0.x = fmaf(a, e0.x, r0.x); o0.y = fmaf(a, e0.y, r0.y);
  o0.z = fmaf(a, e0.z, r0.z); o0.w = fmaf(a, e0.w, r0.w);
  o1.x = fmaf(a, e1.x, r1.x); o1.y = fmaf(a, e1.y, r1.y);
  o1.z = fmaf(a, e1.z, r1.z); o1.w = fmaf(a, e1.w, r1.w);
  out[i0] = o0;
  out[i1] = o1;
}

extern "C" void kernel_launch(void* const* d_in, const int* in_sizes, int n_in,
                              void* d_out, int out_size, void* d_ws, size_t ws_size,
                              hipStream_t stream) {
  const float* raw_res = (const float*)d_in[0];
  const float* rel_res = (const float*)d_in[1];
  const float* raw_g   = (const float*)d_in[2];
  const float* spec_g  = (const float*)d_in[3];
  const float* rel_g   = (const float*)d_in[4];
  const float* gamma   = (const float*)d_in[5];
  const float* beta    = (const float*)d_in[6];
  const float* w1      = (const float*)d_in[7];
  const float* b1      = (const float*)d_in[8];
  const float* w2      = (const float*)d_in[9];
  const float* b2      = (const float*)d_in[10];

  float* out = (float*)d_out;
  // Scratch lives inside d_out's main region; K4 overwrites it afterwards.
  //   gnT:      out[0 .. 98303]            (3072*32 floats)
  //   partials: out[131072 .. 2228223]     (64*32*1024 floats)
  //   alpha:    out[67108864 .. 67108895]  (the real alpha output slot)
  float* gnT      = out;
  float* partials = out + 131072;
  float* alpha    = out + (size_t)B_ * T_ * D_;   // 67108864

  ln_kernel<<<dim3(B_), dim3(256), 0, stream>>>(raw_g, spec_g, rel_g, gamma, beta, gnT);
  gate_gemm<<<dim3(16, 16), dim3(256), 0, stream>>>(gnT, w1, partials);
  gate_finish<<<dim3(B_), dim3(256), 0, stream>>>(partials, b1, w2, b2, alpha);
  fuse_kernel<<<dim3(1024, B_), dim3(256), 0, stream>>>(
      (const float4*)raw_res, (const float4*)rel_res, alpha, (float4*)d_out);
}